// Round 3
// baseline (463.577 us; speedup 1.0000x reference)
//
#include <hip/hip_runtime.h>
#include <hip/hip_bf16.h>

#define OUTF 12288
#define INF  8192
#define MTOT 512

#define BM 128
#define BN 96
#define BK 64
#define NKT 128           // K-steps (= quant groups)

typedef _Float16 h2 __attribute__((ext_vector_type(2)));
typedef _Float16 h8 __attribute__((ext_vector_type(8)));
typedef float    f4 __attribute__((ext_vector_type(4)));

union U2 { unsigned int u; h2 h; };

// ---------------------------------------------------------------------------
// x convert: fp32 -> fp16 in the per-16-block k-permutation the dequant path
// produces (pair-word q holds orig (q, q+8)).  Shared A/B permutation cancels
// inside MFMA.
// ---------------------------------------------------------------------------
__global__ __launch_bounds__(256) void xconvert(const float* __restrict__ x,
                                                _Float16* __restrict__ xh)
{
    int t = blockIdx.x * 256 + threadIdx.x;
    const float4* src = (const float4*)(x + (size_t)t * 16);
    float4 a = src[0];
    float4 b = src[1];
    float4 c = src[2];
    float4 d = src[3];
    U2 o0, o1, o2, o3, o4, o5, o6, o7;
    o0.h = h2{(_Float16)a.x, (_Float16)c.x};
    o1.h = h2{(_Float16)a.y, (_Float16)c.y};
    o2.h = h2{(_Float16)a.z, (_Float16)c.z};
    o3.h = h2{(_Float16)a.w, (_Float16)c.w};
    o4.h = h2{(_Float16)b.x, (_Float16)d.x};
    o5.h = h2{(_Float16)b.y, (_Float16)d.y};
    o6.h = h2{(_Float16)b.z, (_Float16)d.z};
    o7.h = h2{(_Float16)b.w, (_Float16)d.w};
    uint4* dst = (uint4*)(xh + (size_t)t * 16);
    dst[0] = make_uint4(o0.u, o1.u, o2.u, o3.u);
    dst[1] = make_uint4(o4.u, o5.u, o6.u, o7.u);
}

// ---------------------------------------------------------------------------
// Fused dequant + GEMM.  BM=128 BN=96 BK=64, 384 threads (6 waves, 2x3 grid of
// 64x32 wave tiles).  A and w are reg-staged with ~1.3-iteration prefetch
// depth; barriers are lgkmcnt(0)-only (no vmcnt drain) since all cross-thread
// LDS data arrives via ds_write.  grid 512 = 2 blocks/CU, 12 waves/CU.
// ---------------------------------------------------------------------------
__global__ __launch_bounds__(384, 3) void gql_mfma(
    const _Float16* __restrict__ xh,
    const int*      __restrict__ wp,
    const float*    __restrict__ wsc,
    const float*    __restrict__ wbi,
    float*          __restrict__ out)
{
    __shared__ __align__(16) unsigned char ldsA[2][BM * BK * 2];  // 2 x 16 KB
    __shared__ __align__(16) unsigned char ldsB[2][BN * BK * 2];  // 2 x 12 KB

    const int tid  = threadIdx.x;
    const int lane = tid & 63;
    const int wv   = tid >> 6;               // 0..5
    const int wr   = (wv >= 3) ? 1 : 0;      // wave row (64 rows)
    const int wc   = wv - wr * 3;            // wave col 0..2 (32 cols)

    // XCD m-affinity swizzle (blockIdx round-robins XCDs): XCD pair p owns
    // M-panel p -> per-XCD x footprint = 2 MB fp16, L2-resident.
    const int xcd = blockIdx.x & 7;
    const int jt  = blockIdx.x >> 3;         // 0..63
    const int m0  = (xcd >> 1) * BM;
    const int n0  = ((xcd & 1) * 64 + jt) * BN;

    // ---- A staging map: 16 KB tile; chunks 0,1 = all 384 threads, chunk 2 =
    //      threads 0..255.  Global source pre-swizzled so LDS layout is the
    //      XOR-swizzled tile while ds_write addresses stay linear.
    const _Float16* asrc[3];
    int aldsoff[3];
#pragma unroll
    for (int c = 0; c < 3; ++c) {
        int L    = (c < 2) ? (c * 6144 + tid * 16) : (12288 + tid * 16);
        int row  = L >> 7;
        int ksrc = (L & 127) ^ ((row & 7) << 4);
        asrc[c]    = xh + (size_t)(m0 + row) * INF + (ksrc >> 1);
        aldsoff[c] = L;
    }

    // ---- B staging: 96 rows x 4 uint4 = 384 -> exactly one per thread
    const int brow = tid >> 2;               // 0..95
    const int bblk = tid & 3;
    const size_t wpo = (size_t)(n0 + brow) * 2048 + bblk * 4;
    const int sco = (n0 + brow) * 128;
    const int bw0 = brow * 128 + ((bblk * 32) ^ ((brow & 7) << 4));

    // ---- fragment LDS byte offsets (constant over K loop)
    int aoff[2][4], boff[2][2];
#pragma unroll
    for (int kk = 0; kk < 2; ++kk) {
        int kb = kk * 64 + ((lane >> 4) << 4);
#pragma unroll
        for (int i = 0; i < 4; ++i) {
            int row = wr * 64 + i * 16 + (lane & 15);
            aoff[kk][i] = row * 128 + (kb ^ ((row & 7) << 4));
        }
#pragma unroll
        for (int j = 0; j < 2; ++j) {
            int col = wc * 32 + j * 16 + (lane & 15);
            boff[kk][j] = col * 128 + (kb ^ ((col & 7) << 4));
        }
    }

    f4 acc[4][2];
#pragma unroll
    for (int i = 0; i < 4; ++i)
#pragma unroll
        for (int j = 0; j < 2; ++j)
            acc[i][j] = f4{0.f, 0.f, 0.f, 0.f};

    auto loadA = [&](int kt, uint4* ar) {
        ar[0] = *(const uint4*)(asrc[0] + kt * 64);
        ar[1] = *(const uint4*)(asrc[1] + kt * 64);
        if (tid < 256) ar[2] = *(const uint4*)(asrc[2] + kt * 64);
    };
    auto writeA = [&](const uint4* ar, int buf) {
        *(uint4*)(&ldsA[buf][aldsoff[0]]) = ar[0];
        *(uint4*)(&ldsA[buf][aldsoff[1]]) = ar[1];
        if (tid < 256) *(uint4*)(&ldsA[buf][aldsoff[2]]) = ar[2];
    };
    auto loadB = [&](int kt, uint4& w, float& s, float& b) {
        w = *(const uint4*)(wp + wpo + (size_t)kt * 16);
        s = wsc[sco + kt];
        b = wbi[sco + kt];
    };

    // packed-fp16 dequant: nibble as fp16 subnormal n*2^-24, (c*4096)*(s*4096)+b
    auto dequant = [&](uint4 w, float s, float b, int buf) {
        _Float16 sh = (_Float16)(s * 4096.0f);
        _Float16 bh = (_Float16)b;
        h2 S  = h2{sh, sh};
        h2 Bv = h2{bh, bh};
        h2 K  = h2{(_Float16)4096.0f, (_Float16)4096.0f};
        unsigned int wa[4] = {w.x, w.y, w.z, w.w};
        unsigned int ow[8];
#pragma unroll
        for (int j = 0; j < 4; ++j) {
            unsigned int t2 = wa[j] | (wa[j] << 8);
            U2 c02, c13, r02, r13;
            c02.u = t2 & 0x000F000Fu;
            c13.u = (t2 >> 4) & 0x000F000Fu;
            r02.h = (c02.h * K) * S + Bv;
            r13.h = (c13.h * K) * S + Bv;
            ow[j]     = r02.u;
            ow[4 + j] = r13.u;
        }
        *(uint4*)(&ldsB[buf][bw0])      = make_uint4(ow[0], ow[1], ow[2], ow[3]);
        *(uint4*)(&ldsB[buf][bw0 ^ 16]) = make_uint4(ow[4], ow[5], ow[6], ow[7]);
    };

    auto compute = [&](int buf) {
#pragma unroll
        for (int kk = 0; kk < 2; ++kk) {
            h8 af[4], bf[2];
#pragma unroll
            for (int i = 0; i < 4; ++i) af[i] = *(const h8*)(&ldsA[buf][aoff[kk][i]]);
#pragma unroll
            for (int j = 0; j < 2; ++j) bf[j] = *(const h8*)(&ldsB[buf][boff[kk][j]]);
#pragma unroll
            for (int i = 0; i < 4; ++i)
#pragma unroll
                for (int j = 0; j < 2; ++j)
                    acc[i][j] = __builtin_amdgcn_mfma_f32_16x16x32_f16(af[i], bf[j], acc[i][j], 0, 0, 0);
        }
    };

    // lgkm-only barrier: ds_writes must land; global loads stay in flight.
#define LBAR() do { asm volatile("s_waitcnt lgkmcnt(0)" ::: "memory"); \
                    __builtin_amdgcn_s_barrier(); } while (0)

    uint4 arP[3], arQ[3];
    uint4 wwP; float sP, bP;
    uint4 wwQ; float sQ, bQ;

    // ---- prologue: stage kt0 through regs; leave kt1 loads in flight
    loadA(0, arP); loadB(0, wwP, sP, bP);
    writeA(arP, 0); dequant(wwP, sP, bP, 0);
    loadA(1, arP); loadB(1, wwP, sP, bP);
    LBAR();

    // ---- main loop: 2 K-steps per iteration
    for (int kt = 0; kt < NKT - 2; kt += 2) {
        loadA(kt + 2, arQ); loadB(kt + 2, wwQ, sQ, bQ);   // issue early
        writeA(arP, 1); dequant(wwP, sP, bP, 1);          // stage kt+1
        compute(0);                                        // consume kt
        LBAR();

        loadA(kt + 3, arP); loadB(kt + 3, wwP, sP, bP);
        writeA(arQ, 0); dequant(wwQ, sQ, bQ, 0);
        compute(1);
        LBAR();
    }

    // ---- tail: kt = 126, 127  (arP/wwP hold kt=127)
    writeA(arP, 1); dequant(wwP, sP, bP, 1);
    compute(0);
    LBAR();
    compute(1);

    // ---- epilogue: C frag col = lane&15, row = (lane>>4)*4 + r
    const int cr = (lane >> 4) << 2;
    const int cc = lane & 15;
#pragma unroll
    for (int i = 0; i < 4; ++i)
#pragma unroll
        for (int j = 0; j < 2; ++j) {
            int grow = m0 + wr * 64 + i * 16 + cr;
            int gcol = n0 + wc * 32 + j * 16 + cc;
            float* p = out + (size_t)grow * OUTF + gcol;
            p[0 * OUTF] = acc[i][j][0];
            p[1 * OUTF] = acc[i][j][1];
            p[2 * OUTF] = acc[i][j][2];
            p[3 * OUTF] = acc[i][j][3];
        }
#undef LBAR
}

// ---------------------------------------------------------------------------
extern "C" void kernel_launch(void* const* d_in, const int* in_sizes, int n_in,
                              void* d_out, int out_size, void* d_ws, size_t ws_size,
                              hipStream_t stream)
{
    const float* x  = (const float*)d_in[0];
    const int*   wq = (const int*)d_in[1];
    const float* ws = (const float*)d_in[2];
    const float* wb = (const float*)d_in[3];
    float* o        = (float*)d_out;
    _Float16* xh    = (_Float16*)d_ws;      // 8 MB staging

    xconvert<<<(MTOT * (size_t)INF / 16) / 256, 256, 0, stream>>>(x, xh);
    gql_mfma<<<(MTOT / BM) * (OUTF / BN), 384, 0, stream>>>(xh, wq, ws, wb, o);
}

// Round 6
// 342.246 us; speedup vs baseline: 1.3545x; 1.3545x over previous
//
#include <hip/hip_runtime.h>
#include <hip/hip_bf16.h>

#define OUTF 12288
#define INF  8192
#define MTOT 512

#define BM 128
#define BN 64
#define BK 64
#define NKT 128           // K-steps (= quant groups)

typedef _Float16 h2 __attribute__((ext_vector_type(2)));
typedef _Float16 h8 __attribute__((ext_vector_type(8)));
typedef float    f4 __attribute__((ext_vector_type(4)));

union U2 { unsigned int u; h2 h; };

// ---------------------------------------------------------------------------
// x convert: fp32 -> fp16 in the per-16-block k-permutation the dequant path
// produces (pair-word q holds orig (q, q+8)).  Shared A/B permutation cancels
// inside MFMA.
// ---------------------------------------------------------------------------
__global__ __launch_bounds__(256) void xconvert(const float* __restrict__ x,
                                                _Float16* __restrict__ xh)
{
    int t = blockIdx.x * 256 + threadIdx.x;
    const float4* src = (const float4*)(x + (size_t)t * 16);
    float4 a = src[0];
    float4 b = src[1];
    float4 c = src[2];
    float4 d = src[3];
    U2 o0, o1, o2, o3, o4, o5, o6, o7;
    o0.h = h2{(_Float16)a.x, (_Float16)c.x};
    o1.h = h2{(_Float16)a.y, (_Float16)c.y};
    o2.h = h2{(_Float16)a.z, (_Float16)c.z};
    o3.h = h2{(_Float16)a.w, (_Float16)c.w};
    o4.h = h2{(_Float16)b.x, (_Float16)d.x};
    o5.h = h2{(_Float16)b.y, (_Float16)d.y};
    o6.h = h2{(_Float16)b.z, (_Float16)d.z};
    o7.h = h2{(_Float16)b.w, (_Float16)d.w};
    uint4* dst = (uint4*)(xh + (size_t)t * 16);
    dst[0] = make_uint4(o0.u, o1.u, o2.u, o3.u);
    dst[1] = make_uint4(o4.u, o5.u, o6.u, o7.u);
}

// ---------------------------------------------------------------------------
// Fused dequant + GEMM.  Round-2 structure (BM=128 BN=64 BK=64, 256 thr,
// 2x2 waves of 64x32 tiles, n-disjoint XCD swizzle) with prefetch depth
// raised to ~2.7 phases: quad-buffered A via global_load_lds + 4-slot w-reg
// rotation; counted KBAR(vmcnt(14)) keeps 2 future phases in flight across
// every barrier.  LDS 80 KB -> 2 blocks/CU.
// ---------------------------------------------------------------------------
__global__ __launch_bounds__(256, 2) void gql_mfma(
    const _Float16* __restrict__ xh,
    const int*      __restrict__ wp,
    const float*    __restrict__ wsc,
    const float*    __restrict__ wbi,
    float*          __restrict__ out)
{
    __shared__ __align__(16) unsigned char ldsA[4][BM * BK * 2];  // 4 x 16 KB
    __shared__ __align__(16) unsigned char ldsB[2][BN * BK * 2];  // 2 x  8 KB

    const int tid  = threadIdx.x;
    const int lane = tid & 63;
    const int wv   = tid >> 6;
    const int wr   = wv >> 1;          // wave row 0..1 (64 rows)
    const int wc   = wv & 1;           // wave col 0..1 (32 cols)

    // n-disjoint XCD swizzle (768 % 8 == 0): XCD x owns n-tiles [24x, 24x+24)
    // -> per-XCD w slice fetched once from HBM, m-re-reads served by L2.
    const int swz = (blockIdx.x & 7) * 96 + (blockIdx.x >> 3);
    const int m0  = (swz & 3) * BM;    // 4 M tiles
    const int n0  = (swz >> 2) * BN;   // 192 N tiles

    // ---- A staging: 4 x 16B per thread via global_load_lds; global source
    //      pre-swizzled so the linear LDS destination lands XOR-swizzled.
    const _Float16* asrc[4];
#pragma unroll
    for (int ia = 0; ia < 4; ++ia) {
        int L    = ia * 4096 + tid * 16;            // linear LDS byte
        int row  = L >> 7;
        int ksrc = (L & 127) ^ ((row & 7) << 4);
        asrc[ia] = xh + (size_t)(m0 + row) * INF + (ksrc >> 1);
    }

    // ---- B staging: thread owns out-row tid>>2, 4-word block tid&3
    const int brow = tid >> 2;                       // 0..63
    const int bblk = tid & 3;
    const size_t wpo = (size_t)(n0 + brow) * 2048 + bblk * 4;
    const int sco = (n0 + brow) * 128;
    const int bw0 = brow * 128 + ((bblk * 32) ^ ((brow & 7) << 4));

    // ---- fragment LDS byte offsets (constant over K loop)
    int aoff[2][4], boff[2][2];
#pragma unroll
    for (int kk = 0; kk < 2; ++kk) {
        int kb = kk * 64 + ((lane >> 4) << 4);
#pragma unroll
        for (int i = 0; i < 4; ++i) {
            int row = wr * 64 + i * 16 + (lane & 15);
            aoff[kk][i] = row * 128 + (kb ^ ((row & 7) << 4));
        }
#pragma unroll
        for (int j = 0; j < 2; ++j) {
            int col = wc * 32 + j * 16 + (lane & 15);
            boff[kk][j] = col * 128 + (kb ^ ((col & 7) << 4));
        }
    }

    f4 acc[4][2];
#pragma unroll
    for (int i = 0; i < 4; ++i)
#pragma unroll
        for (int j = 0; j < 2; ++j)
            acc[i][j] = f4{0.f, 0.f, 0.f, 0.f};

    auto stageA = [&](int kt, int buf) {
#pragma unroll
        for (int ia = 0; ia < 4; ++ia)
            __builtin_amdgcn_global_load_lds(
                (const __attribute__((address_space(1))) void*)(asrc[ia] + kt * 64),
                (__attribute__((address_space(3))) void*)(&ldsA[buf][ia * 4096 + tid * 16]),
                16, 0, 0);
        // keep glds older than the subsequent w loads in the vmem FIFO
        __builtin_amdgcn_sched_barrier(0);
    };

    auto loadB = [&](int kt, uint4& w, float& s, float& b) {
        w = *(const uint4*)(wp + wpo + (size_t)kt * 16);   // 3 vmem ops total
        s = wsc[sco + kt];
        b = wbi[sco + kt];
    };

    // packed-fp16 dequant: nibble as fp16 subnormal n*2^-24, (c*4096)*(s*4096)+b
    auto dequant = [&](uint4 w, float s, float b, int buf) {
        _Float16 sh = (_Float16)(s * 4096.0f);
        _Float16 bh = (_Float16)b;
        h2 S  = h2{sh, sh};
        h2 Bv = h2{bh, bh};
        h2 K  = h2{(_Float16)4096.0f, (_Float16)4096.0f};
        unsigned int wa[4] = {w.x, w.y, w.z, w.w};
        unsigned int ow[8];
#pragma unroll
        for (int j = 0; j < 4; ++j) {
            unsigned int t2 = wa[j] | (wa[j] << 8);
            U2 c02, c13, r02, r13;
            c02.u = t2 & 0x000F000Fu;
            c13.u = (t2 >> 4) & 0x000F000Fu;
            r02.h = (c02.h * K) * S + Bv;
            r13.h = (c13.h * K) * S + Bv;
            ow[j]     = r02.u;
            ow[4 + j] = r13.u;
        }
        *(uint4*)(&ldsB[buf][bw0])      = make_uint4(ow[0], ow[1], ow[2], ow[3]);
        *(uint4*)(&ldsB[buf][bw0 ^ 16]) = make_uint4(ow[4], ow[5], ow[6], ow[7]);
    };

    auto compute = [&](int bufA, int bufB) {
#pragma unroll
        for (int kk = 0; kk < 2; ++kk) {
            h8 af[4], bf[2];
#pragma unroll
            for (int i = 0; i < 4; ++i) af[i] = *(const h8*)(&ldsA[bufA][aoff[kk][i]]);
#pragma unroll
            for (int j = 0; j < 2; ++j) bf[j] = *(const h8*)(&ldsB[bufB][boff[kk][j]]);
#pragma unroll
            for (int i = 0; i < 4; ++i)
#pragma unroll
                for (int j = 0; j < 2; ++j)
                    acc[i][j] = __builtin_amdgcn_mfma_f32_16x16x32_f16(af[i], bf[j], acc[i][j], 0, 0, 0);
        }
    };

    // barrier: ds_writes drained; keep the newest 14 vmem ops (= 2 future
    // phases of A[4]+B[3]) in flight.
#define KBAR() do { asm volatile("s_waitcnt vmcnt(14) lgkmcnt(0)" ::: "memory"); \
                    __builtin_amdgcn_s_barrier(); } while (0)

    uint4 w0, w1, w2, w3; float s0, s1, s2, s3, b0, b1, b2, b3;

    // ---- prologue: stage phases 0..2; dequant phase 0 (drains A0,B0)
    stageA(0, 0); loadB(0, w0, s0, b0);
    stageA(1, 1); loadB(1, w1, s1, b1);
    stageA(2, 2); loadB(2, w2, s2, b2);
    dequant(w0, s0, b0, 0);
    KBAR();

    // ---- main loop: 4 phases per iteration; prefetch distance 3
    for (int kt = 0; kt < NKT; kt += 4) {
        // phase kt+0: compute buf0/B0, prep kt+1 into B1, prefetch kt+3
        if (kt + 3 < NKT) { stageA(kt + 3, 3); loadB(kt + 3, w3, s3, b3); }
        compute(0, 0);
        dequant(w1, s1, b1, 1);
        KBAR();
        // phase kt+1
        if (kt + 4 < NKT) { stageA(kt + 4, 0); loadB(kt + 4, w0, s0, b0); }
        compute(1, 1);
        dequant(w2, s2, b2, 0);
        KBAR();
        // phase kt+2
        if (kt + 5 < NKT) { stageA(kt + 5, 1); loadB(kt + 5, w1, s1, b1); }
        compute(2, 0);
        dequant(w3, s3, b3, 1);
        KBAR();
        // phase kt+3
        if (kt + 6 < NKT) { stageA(kt + 6, 2); loadB(kt + 6, w2, s2, b2); }
        compute(3, 1);
        if (kt + 4 < NKT) dequant(w0, s0, b0, 0);
        KBAR();
    }

    // ---- epilogue: C frag col = lane&15, row = (lane>>4)*4 + r
    const int cr = (lane >> 4) << 2;
    const int cc = lane & 15;
#pragma unroll
    for (int i = 0; i < 4; ++i)
#pragma unroll
        for (int j = 0; j < 2; ++j) {
            int grow = m0 + wr * 64 + i * 16 + cr;
            int gcol = n0 + wc * 32 + j * 16 + cc;
            float* p = out + (size_t)grow * OUTF + gcol;
            p[0 * OUTF] = acc[i][j][0];
            p[1 * OUTF] = acc[i][j][1];
            p[2 * OUTF] = acc[i][j][2];
            p[3 * OUTF] = acc[i][j][3];
        }
#undef KBAR
}

// ---------------------------------------------------------------------------
extern "C" void kernel_launch(void* const* d_in, const int* in_sizes, int n_in,
                              void* d_out, int out_size, void* d_ws, size_t ws_size,
                              hipStream_t stream)
{
    const float* x  = (const float*)d_in[0];
    const int*   wq = (const int*)d_in[1];
    const float* ws = (const float*)d_in[2];
    const float* wb = (const float*)d_in[3];
    float* o        = (float*)d_out;
    _Float16* xh    = (_Float16*)d_ws;      // 8 MB staging

    xconvert<<<(MTOT * (size_t)INF / 16) / 256, 256, 0, stream>>>(x, xh);
    gql_mfma<<<(MTOT / BM) * (OUTF / BN), 256, 0, stream>>>(xh, wq, ws, wb, o);
}